// Round 18
// baseline (131.260 us; speedup 1.0000x reference)
//
#include <hip/hip_runtime.h>
#include <stdint.h>
#include <math.h>

#define HID 64
#define PI_F 3.14159262235897933f

typedef float v2f __attribute__((ext_vector_type(2)));

__device__ __forceinline__ unsigned short f2bf(float f) {   // round-to-nearest-even
    unsigned u = __float_as_uint(f);
    return (unsigned short)((u + 0x7FFFu + ((u >> 16) & 1u)) >> 16);
}
__device__ __forceinline__ float bflo(unsigned v) { return __uint_as_float(v << 16); }
__device__ __forceinline__ float bfhi(unsigned v) { return __uint_as_float(v & 0xFFFF0000u); }

// ---------- fused prep: bf16 quat table + tail histogram + PADDED bf16 entity copy ----------
// ent16p row layout: 32 x uint4; slot j = {x(2j,2j+1), y(2j,2j+1), z(2j,2j+1), 0}
__global__ void prep(const float* __restrict__ rel, uint2* __restrict__ quat16, int nrel,
                     const int* __restrict__ eidx, int E, int* __restrict__ hist,
                     const float* __restrict__ ent, uint4* __restrict__ ent16p, int nconv,
                     int qblocks, int eblocks) {
    const int b = blockIdx.x;
    if (b < qblocks) {
        int i = b * 256 + threadIdx.x;
        if (i >= nrel * HID) return;
        int r = i >> 6, j = i & 63;
        const float* base = rel + (size_t)r * 4 * HID;
        float rx = base[j];
        float ry = base[HID + j];
        float rz = base[2 * HID + j];
        float th = base[3 * HID + j];
        float theta = th * PI_F;
        float sn = sinf(theta);
        float w  = cosf(theta);
        float tx = sn * rx, ty = sn * ry, tz = sn * rz;
        float norm = sqrtf(tx * tx + ty * ty + tz * tz);
        float inv = 1.0f / fmaxf(norm, 1e-12f);
        float s = sqrtf(fmaxf(1.0f - w * w, 0.0f));
        float ux = s * tx * inv, uy = s * ty * inv, uz = s * tz * inv;
        quat16[i] = make_uint2(((unsigned)f2bf(ux) << 16) | f2bf(w),
                               ((unsigned)f2bf(uz) << 16) | f2bf(uy));
    } else if (b < qblocks + eblocks) {
        int e = (b - qblocks) * 256 + threadIdx.x;
        if (e >= E) return;
        atomicAdd(hist + eidx[2 * E + e], 1);
    } else {
        int u = (b - qblocks - eblocks) * 256 + threadIdx.x;
        if (u >= nconv) return;                      // nconv = n_ent * 32
        int row = u >> 5, j = u & 31;
        const float* base = ent + (size_t)row * 192;
        float2 xs = *(const float2*)(base + 2 * j);
        float2 ys = *(const float2*)(base + 64 + 2 * j);
        float2 zs = *(const float2*)(base + 128 + 2 * j);
        ent16p[u] = make_uint4(((unsigned)f2bf(xs.y) << 16) | f2bf(xs.x),
                               ((unsigned)f2bf(ys.y) << 16) | f2bf(ys.x),
                               ((unsigned)f2bf(zs.y) << 16) | f2bf(zs.x),
                               0u);
    }
}

// ---------- scan1: per-256-chunk exclusive scan; emits chunk partials + base2 copy ----------
__global__ void scan1(const int* __restrict__ hist, int* __restrict__ base,
                      int* __restrict__ base2, int* __restrict__ partial, int n) {
    __shared__ int buf[256];
    int tid = threadIdx.x;
    int gid = blockIdx.x * 256 + tid;
    int v = (gid < n) ? hist[gid] : 0;
    buf[tid] = v;
    __syncthreads();
    #pragma unroll
    for (int off = 1; off < 256; off <<= 1) {
        int x = (tid >= off) ? buf[tid - off] : 0;
        __syncthreads();
        buf[tid] += x;
        __syncthreads();
    }
    if (gid < n) {
        int bv = buf[tid] - v;            // chunk-local exclusive
        base[gid] = bv;
        base2[gid] = bv;                  // scatter cursor (chunk-local)
    }
    if (tid == 255) partial[blockIdx.x] = buf[255];
}

// ---------- scatter (fused partial-scan): PACKED (head<<9 | rel) ----------
__global__ void scatter_hr(const int* __restrict__ eidx, int E,
                           const int* __restrict__ partial, int nb,
                           int* __restrict__ base2,
                           unsigned* __restrict__ hrp) {
    __shared__ int buf[256];
    const int tid = threadIdx.x;
    int v = (tid < nb) ? partial[tid] : 0;
    buf[tid] = v;
    __syncthreads();
    #pragma unroll
    for (int off = 1; off < 256; off <<= 1) {
        int x = (tid >= off) ? buf[tid - off] : 0;
        __syncthreads();
        buf[tid] += x;
        __syncthreads();
    }
    int ex = buf[tid] - v;                // exclusive prefix of chunk tid
    __syncthreads();
    buf[tid] = ex;
    __syncthreads();

    int e = blockIdx.x * 256 + tid;
    if (e >= E) return;
    int t = eidx[2 * E + e];
    int pos = buf[t >> 8] + atomicAdd(base2 + t, 1);   // base2 holds chunk-local base
    hrp[pos] = ((unsigned)eidx[e] << 9) | (unsigned)eidx[E + e];
}

// ---------- persistent per-tail pass: 32 lanes/edge, 2 edges/wave ----------
// Padded-row layout: ONE b128 per head row per lane (was 3 b32) -> 3 mem inst/iter.
// No max-tracking (alpha bounded; validated R7-R17). Lane owns dims {2j, 2j+1}.
__global__ void __launch_bounds__(256)
seg_reduce(const uint4* __restrict__ ent16p,  // padded bf16 rows, 32 uint4/row
           const uint4* __restrict__ quat4,   // bf16 quat rows, 32 uint4/row
           const unsigned* __restrict__ hrp,
           const int* __restrict__ base,
           const int* __restrict__ partial, int nb,
           int n_ent, int E,
           float* __restrict__ out) {
    __shared__ int buf[256];
    {   // prologue: exclusive scan of chunk partials (redundant per block)
        const int tid = threadIdx.x;
        int v = (tid < nb) ? partial[tid] : 0;
        buf[tid] = v;
        __syncthreads();
        #pragma unroll
        for (int off = 1; off < 256; off <<= 1) {
            int x = (tid >= off) ? buf[tid - off] : 0;
            __syncthreads();
            buf[tid] += x;
            __syncthreads();
        }
        int ex = buf[tid] - v;
        __syncthreads();
        buf[tid] = ex;
        __syncthreads();
    }

    const int lane = threadIdx.x & 63;
    const int half = lane >> 5;           // edge slot 0..1
    const int j    = lane & 31;           // dim pair: dims 2j, 2j+1
    const int wid = (blockIdx.x * blockDim.x + threadIdx.x) >> 6;
    const int nw  = (gridDim.x * blockDim.x) >> 6;

    for (int t = wid; t < n_ent; t += nw) {
        int start = base[t] + buf[t >> 8];
        int end   = (t + 1 < n_ent) ? (base[t + 1] + buf[(t + 1) >> 8]) : E;
        v2f* o2 = (v2f*)(out + (size_t)t * (4 * HID));
        const int ob0 = half * 64 + j;     // v2f slots
        const int ob1 = ob0 + 32;
        if (start == end) {
            v2f z = {0.f, 0.f};
            o2[ob0] = z;
            o2[ob1] = z;
            continue;
        }
        int last = end - 1;

        uint4 ku = ent16p[(size_t)t * 32 + j];
        v2f kx = {bflo(ku.x), bfhi(ku.x)};
        v2f ky = {bflo(ku.y), bfhi(ku.y)};
        v2f kz = {bflo(ku.z), bfhi(ku.z)};

        float dnm = 0.0f;
        v2f fx = {0.f, 0.f}, fy = fx, fz = fx, fw = fx;

        for (int kk = start; kk < end; kk += 2) {
            int e = kk + half;
            bool valid = (e < end);
            unsigned her = hrp[min(e, last)];
            unsigned hidx = her >> 9;
            unsigned ridx = her & 511u;

            uint4 ua = ent16p[(size_t)hidx * 32 + j];   // ONE b128 gather
            uint4 qa = quat4[ridx * 32 + j];

            v2f ex = {bflo(ua.x), bfhi(ua.x)};
            v2f ey = {bflo(ua.y), bfhi(ua.y)};
            v2f ez = {bflo(ua.z), bfhi(ua.z)};
            v2f w  = {bflo(qa.x), bflo(qa.z)};
            v2f ux = {bfhi(qa.x), bfhi(qa.z)};
            v2f uy = {bflo(qa.y), bflo(qa.w)};
            v2f uz = {bfhi(qa.y), bfhi(qa.w)};

            v2f rqx = w * ex + uy * ez - uz * ey;
            v2f rqy = w * ey + uz * ex - ux * ez;
            v2f rqz = w * ez + ux * ey - uy * ex;
            v2f rqw = -(ux * ex + uy * ey + uz * ez);

            v2f p2 = kx * rqx + ky * rqy + kz * rqz;
            float p = p2.x + p2.y;
            p += __shfl_xor(p, 1, 64);
            p += __shfl_xor(p, 2, 64);
            p += __shfl_xor(p, 4, 64);
            p += __shfl_xor(p, 8, 64);
            p += __shfl_xor(p, 16, 64);

            float pe = valid ? __expf(p * 0.0625f) : 0.0f;
            v2f pe2 = {pe, pe};
            dnm += pe;
            fx += pe2 * rqx;
            fy += pe2 * rqy;
            fz += pe2 * rqz;
            fw += pe2 * rqw;
        }

        // merge the two edge-slot halves (plain sums)
        dnm += __shfl_xor(dnm, 32, 64);
        fx.x += __shfl_xor(fx.x, 32, 64); fx.y += __shfl_xor(fx.y, 32, 64);
        fy.x += __shfl_xor(fy.x, 32, 64); fy.y += __shfl_xor(fy.y, 32, 64);
        fz.x += __shfl_xor(fz.x, 32, 64); fz.y += __shfl_xor(fz.y, 32, 64);
        fw.x += __shfl_xor(fw.x, 32, 64); fw.y += __shfl_xor(fw.y, 32, 64);

        float inv = (dnm > 0.0f) ? 1.0f / dnm : 0.0f;
        v2f s0 = half ? fz : fx;
        v2f s1 = half ? fw : fy;
        v2f r0 = {s0.x * inv, s0.y * inv};
        v2f r1 = {s1.x * inv, s1.y * inv};
        o2[ob0] = r0;
        o2[ob1] = r1;
    }
}

extern "C" void kernel_launch(void* const* d_in, const int* in_sizes, int n_in,
                              void* d_out, int out_size, void* d_ws, size_t ws_size,
                              hipStream_t stream) {
    const float* ent  = (const float*)d_in[0];
    const float* rel  = (const float*)d_in[1];
    const int*   eidx = (const int*)d_in[2];
    float* out = (float*)d_out;

    const int n_ent = in_sizes[0] / (3 * HID);
    const int n_rel = in_sizes[1] / (4 * HID);
    const int E     = in_sizes[2] / 3;

    // Workspace layout
    uint8_t* wp = (uint8_t*)d_ws;
    unsigned* hrp = (unsigned*)wp;                   wp += (size_t)E * 4;
    int*  hist    = (int*)wp;                        wp += (size_t)n_ent * 4;
    int*  base    = (int*)wp;                        wp += (size_t)n_ent * 4;
    int*  base2   = (int*)wp;                        wp += (size_t)n_ent * 4;
    int*  partial = (int*)wp;                        wp += 256 * 4;
    wp = (uint8_t*)(((uintptr_t)wp + 15) & ~(uintptr_t)15);
    uint2* quat16 = (uint2*)wp;                      wp += (size_t)n_rel * HID * sizeof(uint2);
    wp = (uint8_t*)(((uintptr_t)wp + 15) & ~(uintptr_t)15);
    uint4* ent16p = (uint4*)wp;                      wp += (size_t)n_ent * 32 * sizeof(uint4);
    (void)ws_size;

    hipMemsetAsync(hist, 0, (size_t)n_ent * 4, stream);

    const int qblocks = (n_rel * HID + 255) / 256;
    const int eblocks = (E + 255) / 256;
    const int nconv   = n_ent * 32;                  // uint4 units (padded rows)
    const int cblocks = (nconv + 255) / 256;
    prep<<<qblocks + eblocks + cblocks, 256, 0, stream>>>(
        rel, quat16, n_rel, eidx, E, hist, ent, ent16p, nconv, qblocks, eblocks);

    const int nb = (n_ent + 255) / 256;              // 196 (<=256)
    scan1<<<nb, 256, 0, stream>>>(hist, base, base2, partial, n_ent);

    scatter_hr<<<eblocks, 256, 0, stream>>>(eidx, E, partial, nb, base2, hrp);

    seg_reduce<<<2048, 256, 0, stream>>>(ent16p, (const uint4*)quat16,
                                         hrp, base, partial, nb, n_ent, E, out);
}

// Round 19
// 129.656 us; speedup vs baseline: 1.0124x; 1.0124x over previous
//
#include <hip/hip_runtime.h>
#include <stdint.h>
#include <math.h>

#define HID 64
#define PI_F 3.14159262235897933f

typedef float v2f __attribute__((ext_vector_type(2)));

__device__ __forceinline__ unsigned short f2bf(float f) {   // round-to-nearest-even
    unsigned u = __float_as_uint(f);
    return (unsigned short)((u + 0x7FFFu + ((u >> 16) & 1u)) >> 16);
}
__device__ __forceinline__ float bflo(unsigned v) { return __uint_as_float(v << 16); }
__device__ __forceinline__ float bfhi(unsigned v) { return __uint_as_float(v & 0xFFFF0000u); }

// ---------- dispatch 2: tail histogram only (shortest serial prefix for the scan) ----------
__global__ void hist_tails(const int* __restrict__ eidx, int E, int* __restrict__ hist) {
    int e = blockIdx.x * blockDim.x + threadIdx.x;
    if (e >= E) return;
    atomicAdd(hist + eidx[2 * E + e], 1);
}

// ---------- dispatch 3: per-256-chunk exclusive scan; emits chunk partials + base2 copy ----------
__global__ void scan1(const int* __restrict__ hist, int* __restrict__ base,
                      int* __restrict__ base2, int* __restrict__ partial, int n) {
    __shared__ int buf[256];
    int tid = threadIdx.x;
    int gid = blockIdx.x * 256 + tid;
    int v = (gid < n) ? hist[gid] : 0;
    buf[tid] = v;
    __syncthreads();
    #pragma unroll
    for (int off = 1; off < 256; off <<= 1) {
        int x = (tid >= off) ? buf[tid - off] : 0;
        __syncthreads();
        buf[tid] += x;
        __syncthreads();
    }
    if (gid < n) {
        int bv = buf[tid] - v;            // chunk-local exclusive
        base[gid] = bv;
        base2[gid] = bv;                  // scatter cursor (chunk-local)
    }
    if (tid == 255) partial[blockIdx.x] = buf[255];
}

// ---------- dispatch 4: scatter ∥ quat table ∥ bf16 entity conversion (disjoint blocks) ----------
__global__ void prep2(const float* __restrict__ rel, uint2* __restrict__ quat16, int nrel,
                      const int* __restrict__ eidx, int E,
                      const float* __restrict__ ent, uint4* __restrict__ ent16, int nconv,
                      const int* __restrict__ partial, int nb,
                      int* __restrict__ base2, unsigned* __restrict__ hrp,
                      int qblocks, int cblocks) {
    const int b = blockIdx.x;
    if (b < qblocks) {
        int i = b * 256 + threadIdx.x;
        if (i >= nrel * HID) return;
        int r = i >> 6, j = i & 63;
        const float* base = rel + (size_t)r * 4 * HID;
        float rx = base[j];
        float ry = base[HID + j];
        float rz = base[2 * HID + j];
        float th = base[3 * HID + j];
        float theta = th * PI_F;
        float sn = sinf(theta);
        float w  = cosf(theta);
        float tx = sn * rx, ty = sn * ry, tz = sn * rz;
        float norm = sqrtf(tx * tx + ty * ty + tz * tz);
        float inv = 1.0f / fmaxf(norm, 1e-12f);
        float s = sqrtf(fmaxf(1.0f - w * w, 0.0f));
        float ux = s * tx * inv, uy = s * ty * inv, uz = s * tz * inv;
        quat16[i] = make_uint2(((unsigned)f2bf(ux) << 16) | f2bf(w),
                               ((unsigned)f2bf(uz) << 16) | f2bf(uy));
    } else if (b < qblocks + cblocks) {
        int u = (b - qblocks) * 256 + threadIdx.x;
        if (u >= nconv) return;
        const float4* src = (const float4*)ent + 2 * (size_t)u;
        float4 a = src[0], c = src[1];
        ent16[u] = make_uint4(((unsigned)f2bf(a.y) << 16) | f2bf(a.x),
                              ((unsigned)f2bf(a.w) << 16) | f2bf(a.z),
                              ((unsigned)f2bf(c.y) << 16) | f2bf(c.x),
                              ((unsigned)f2bf(c.w) << 16) | f2bf(c.z));
    } else {
        __shared__ int buf[256];
        const int tid = threadIdx.x;
        int v = (tid < nb) ? partial[tid] : 0;
        buf[tid] = v;
        __syncthreads();
        #pragma unroll
        for (int off = 1; off < 256; off <<= 1) {
            int x = (tid >= off) ? buf[tid - off] : 0;
            __syncthreads();
            buf[tid] += x;
            __syncthreads();
        }
        int ex = buf[tid] - v;            // exclusive prefix of chunk tid
        __syncthreads();
        buf[tid] = ex;
        __syncthreads();

        int e = (b - qblocks - cblocks) * 256 + tid;
        if (e >= E) return;
        int t = eidx[2 * E + e];
        int pos = buf[t >> 8] + atomicAdd(base2 + t, 1);
        hrp[pos] = ((unsigned)eidx[e] << 9) | (unsigned)eidx[E + e];
    }
}

// ---------- persistent per-tail pass: 32 lanes/edge, 2 edges/wave, all-bf16 gathers ----------
// R17 loop verbatim (59 µs best). No max-tracking (alpha bounded; validated R7-R18).
__global__ void __launch_bounds__(256)
seg_reduce(const unsigned* __restrict__ ent32,  // bf16 entity rows, 96 uint32/row
           const uint4* __restrict__ quat4,     // bf16 quat rows, 32 uint4/row
           const unsigned* __restrict__ hrp,
           const int* __restrict__ base,
           const int* __restrict__ partial, int nb,
           int n_ent, int E,
           float* __restrict__ out) {
    __shared__ int buf[256];
    {   // prologue: exclusive scan of chunk partials (redundant per block)
        const int tid = threadIdx.x;
        int v = (tid < nb) ? partial[tid] : 0;
        buf[tid] = v;
        __syncthreads();
        #pragma unroll
        for (int off = 1; off < 256; off <<= 1) {
            int x = (tid >= off) ? buf[tid - off] : 0;
            __syncthreads();
            buf[tid] += x;
            __syncthreads();
        }
        int ex = buf[tid] - v;
        __syncthreads();
        buf[tid] = ex;
        __syncthreads();
    }

    const int lane = threadIdx.x & 63;
    const int half = lane >> 5;           // edge slot 0..1
    const int j    = lane & 31;           // dim pair: dims 2j, 2j+1
    const int wid = (blockIdx.x * blockDim.x + threadIdx.x) >> 6;
    const int nw  = (gridDim.x * blockDim.x) >> 6;

    for (int t = wid; t < n_ent; t += nw) {
        int start = base[t] + buf[t >> 8];
        int end   = (t + 1 < n_ent) ? (base[t + 1] + buf[(t + 1) >> 8]) : E;
        v2f* o2 = (v2f*)(out + (size_t)t * (4 * HID));
        const int ob0 = half * 64 + j;     // v2f slots
        const int ob1 = ob0 + 32;
        if (start == end) {
            v2f z = {0.f, 0.f};
            o2[ob0] = z;
            o2[ob1] = z;
            continue;
        }
        int last = end - 1;

        const unsigned* kb = ent32 + (size_t)t * 96;
        unsigned ku0 = kb[j], ku1 = kb[32 + j], ku2 = kb[64 + j];
        v2f kx = {bflo(ku0), bfhi(ku0)};
        v2f ky = {bflo(ku1), bfhi(ku1)};
        v2f kz = {bflo(ku2), bfhi(ku2)};

        float dnm = 0.0f;
        v2f fx = {0.f, 0.f}, fy = fx, fz = fx, fw = fx;

        for (int kk = start; kk < end; kk += 2) {
            int e = kk + half;
            bool valid = (e < end);
            unsigned her = hrp[min(e, last)];
            unsigned hidx = her >> 9;
            unsigned ridx = her & 511u;

            const unsigned* hb = ent32 + (size_t)hidx * 96;
            unsigned u0 = hb[j], u1 = hb[32 + j], u2 = hb[64 + j];
            uint4 qa = quat4[ridx * 32 + j];

            v2f ex = {bflo(u0), bfhi(u0)};
            v2f ey = {bflo(u1), bfhi(u1)};
            v2f ez = {bflo(u2), bfhi(u2)};
            v2f w  = {bflo(qa.x), bflo(qa.z)};
            v2f ux = {bfhi(qa.x), bfhi(qa.z)};
            v2f uy = {bflo(qa.y), bflo(qa.w)};
            v2f uz = {bfhi(qa.y), bfhi(qa.w)};

            v2f rqx = w * ex + uy * ez - uz * ey;
            v2f rqy = w * ey + uz * ex - ux * ez;
            v2f rqz = w * ez + ux * ey - uy * ex;
            v2f rqw = -(ux * ex + uy * ey + uz * ez);

            v2f p2 = kx * rqx + ky * rqy + kz * rqz;
            float p = p2.x + p2.y;
            p += __shfl_xor(p, 1, 64);
            p += __shfl_xor(p, 2, 64);
            p += __shfl_xor(p, 4, 64);
            p += __shfl_xor(p, 8, 64);
            p += __shfl_xor(p, 16, 64);

            float pe = valid ? __expf(p * 0.0625f) : 0.0f;
            v2f pe2 = {pe, pe};
            dnm += pe;
            fx += pe2 * rqx;
            fy += pe2 * rqy;
            fz += pe2 * rqz;
            fw += pe2 * rqw;
        }

        // merge the two edge-slot halves (plain sums)
        dnm += __shfl_xor(dnm, 32, 64);
        fx.x += __shfl_xor(fx.x, 32, 64); fx.y += __shfl_xor(fx.y, 32, 64);
        fy.x += __shfl_xor(fy.x, 32, 64); fy.y += __shfl_xor(fy.y, 32, 64);
        fz.x += __shfl_xor(fz.x, 32, 64); fz.y += __shfl_xor(fz.y, 32, 64);
        fw.x += __shfl_xor(fw.x, 32, 64); fw.y += __shfl_xor(fw.y, 32, 64);

        float inv = (dnm > 0.0f) ? 1.0f / dnm : 0.0f;
        v2f s0 = half ? fz : fx;
        v2f s1 = half ? fw : fy;
        v2f r0 = {s0.x * inv, s0.y * inv};
        v2f r1 = {s1.x * inv, s1.y * inv};
        o2[ob0] = r0;
        o2[ob1] = r1;
    }
}

extern "C" void kernel_launch(void* const* d_in, const int* in_sizes, int n_in,
                              void* d_out, int out_size, void* d_ws, size_t ws_size,
                              hipStream_t stream) {
    const float* ent  = (const float*)d_in[0];
    const float* rel  = (const float*)d_in[1];
    const int*   eidx = (const int*)d_in[2];
    float* out = (float*)d_out;

    const int n_ent = in_sizes[0] / (3 * HID);
    const int n_rel = in_sizes[1] / (4 * HID);
    const int E     = in_sizes[2] / 3;

    // Workspace layout
    uint8_t* wp = (uint8_t*)d_ws;
    unsigned* hrp = (unsigned*)wp;                   wp += (size_t)E * 4;
    int*  hist    = (int*)wp;                        wp += (size_t)n_ent * 4;
    int*  base    = (int*)wp;                        wp += (size_t)n_ent * 4;
    int*  base2   = (int*)wp;                        wp += (size_t)n_ent * 4;
    int*  partial = (int*)wp;                        wp += 256 * 4;
    wp = (uint8_t*)(((uintptr_t)wp + 15) & ~(uintptr_t)15);
    uint2* quat16 = (uint2*)wp;                      wp += (size_t)n_rel * HID * sizeof(uint2);
    wp = (uint8_t*)(((uintptr_t)wp + 15) & ~(uintptr_t)15);
    uint4* ent16  = (uint4*)wp;                      wp += (size_t)n_ent * 3 * HID * 2;
    (void)ws_size;

    hipMemsetAsync(hist, 0, (size_t)n_ent * 4, stream);

    const int eblocks = (E + 255) / 256;
    hist_tails<<<eblocks, 256, 0, stream>>>(eidx, E, hist);

    const int nb = (n_ent + 255) / 256;              // 196 (<=256)
    scan1<<<nb, 256, 0, stream>>>(hist, base, base2, partial, n_ent);

    const int qblocks = (n_rel * HID + 255) / 256;
    const int nconv   = n_ent * 3 * HID / 8;         // uint4 units
    const int cblocks = (nconv + 255) / 256;
    prep2<<<qblocks + cblocks + eblocks, 256, 0, stream>>>(
        rel, quat16, n_rel, eidx, E, ent, ent16, nconv,
        partial, nb, base2, hrp, qblocks, cblocks);

    seg_reduce<<<2048, 256, 0, stream>>>((const unsigned*)ent16, (const uint4*)quat16,
                                         hrp, base, partial, nb, n_ent, E, out);
}

// Round 20
// 122.760 us; speedup vs baseline: 1.0692x; 1.0562x over previous
//
#include <hip/hip_runtime.h>
#include <stdint.h>
#include <math.h>

#define HID 64
#define PI_F 3.14159262235897933f

typedef float v2f __attribute__((ext_vector_type(2)));

__device__ __forceinline__ unsigned short f2bf(float f) {   // round-to-nearest-even
    unsigned u = __float_as_uint(f);
    return (unsigned short)((u + 0x7FFFu + ((u >> 16) & 1u)) >> 16);
}
__device__ __forceinline__ float bflo(unsigned v) { return __uint_as_float(v << 16); }
__device__ __forceinline__ float bfhi(unsigned v) { return __uint_as_float(v & 0xFFFF0000u); }

// ---------- fused prep: bf16 quat table + tail histogram + bf16 entity copy ----------
__global__ void prep(const float* __restrict__ rel, uint2* __restrict__ quat16, int nrel,
                     const int* __restrict__ eidx, int E, int* __restrict__ hist,
                     const float* __restrict__ ent, uint4* __restrict__ ent16, int nconv,
                     int qblocks, int eblocks) {
    const int b = blockIdx.x;
    if (b < qblocks) {
        int i = b * 256 + threadIdx.x;
        if (i >= nrel * HID) return;
        int r = i >> 6, j = i & 63;
        const float* base = rel + (size_t)r * 4 * HID;
        float rx = base[j];
        float ry = base[HID + j];
        float rz = base[2 * HID + j];
        float th = base[3 * HID + j];
        float theta = th * PI_F;
        float sn = sinf(theta);
        float w  = cosf(theta);
        float tx = sn * rx, ty = sn * ry, tz = sn * rz;
        float norm = sqrtf(tx * tx + ty * ty + tz * tz);
        float inv = 1.0f / fmaxf(norm, 1e-12f);
        float s = sqrtf(fmaxf(1.0f - w * w, 0.0f));
        float ux = s * tx * inv, uy = s * ty * inv, uz = s * tz * inv;
        quat16[i] = make_uint2(((unsigned)f2bf(ux) << 16) | f2bf(w),
                               ((unsigned)f2bf(uz) << 16) | f2bf(uy));
    } else if (b < qblocks + eblocks) {
        int e = (b - qblocks) * 256 + threadIdx.x;
        if (e >= E) return;
        atomicAdd(hist + eidx[2 * E + e], 1);
    } else {
        int u = (b - qblocks - eblocks) * 256 + threadIdx.x;
        if (u >= nconv) return;
        const float4* src = (const float4*)ent + 2 * (size_t)u;
        float4 a = src[0], c = src[1];
        ent16[u] = make_uint4(((unsigned)f2bf(a.y) << 16) | f2bf(a.x),
                              ((unsigned)f2bf(a.w) << 16) | f2bf(a.z),
                              ((unsigned)f2bf(c.y) << 16) | f2bf(c.x),
                              ((unsigned)f2bf(c.w) << 16) | f2bf(c.z));
    }
}

// ---------- scan1: per-256-chunk exclusive scan; emits chunk partials + base2 copy ----------
__global__ void scan1(const int* __restrict__ hist, int* __restrict__ base,
                      int* __restrict__ base2, int* __restrict__ partial, int n) {
    __shared__ int buf[256];
    int tid = threadIdx.x;
    int gid = blockIdx.x * 256 + tid;
    int v = (gid < n) ? hist[gid] : 0;
    buf[tid] = v;
    __syncthreads();
    #pragma unroll
    for (int off = 1; off < 256; off <<= 1) {
        int x = (tid >= off) ? buf[tid - off] : 0;
        __syncthreads();
        buf[tid] += x;
        __syncthreads();
    }
    if (gid < n) {
        int bv = buf[tid] - v;            // chunk-local exclusive
        base[gid] = bv;
        base2[gid] = bv;                  // scatter cursor (chunk-local)
    }
    if (tid == 255) partial[blockIdx.x] = buf[255];
}

// ---------- scatter (fused partial-scan): PACKED (head<<9 | rel) ----------
__global__ void scatter_hr(const int* __restrict__ eidx, int E,
                           const int* __restrict__ partial, int nb,
                           int* __restrict__ base2,
                           unsigned* __restrict__ hrp) {
    __shared__ int buf[256];
    const int tid = threadIdx.x;
    int v = (tid < nb) ? partial[tid] : 0;
    buf[tid] = v;
    __syncthreads();
    #pragma unroll
    for (int off = 1; off < 256; off <<= 1) {
        int x = (tid >= off) ? buf[tid - off] : 0;
        __syncthreads();
        buf[tid] += x;
        __syncthreads();
    }
    int ex = buf[tid] - v;                // exclusive prefix of chunk tid
    __syncthreads();
    buf[tid] = ex;
    __syncthreads();

    int e = blockIdx.x * 256 + tid;
    if (e >= E) return;
    int t = eidx[2 * E + e];
    int pos = buf[t >> 8] + atomicAdd(base2 + t, 1);   // base2 holds chunk-local base
    hrp[pos] = ((unsigned)eidx[e] << 9) | (unsigned)eidx[E + e];
}

// ---------- persistent per-tail pass: 32 lanes/edge, 2 edges/wave, all-bf16 gathers ----------
// No max-tracking (alpha bounded; validated R7-R19). Lane owns dims {2j, 2j+1}.
// Plain cached loads/stores (nt hints regressed: R16). Minimal body, 32 VGPR (R12/R14 lesson).
__global__ void __launch_bounds__(256)
seg_reduce(const unsigned* __restrict__ ent32,  // bf16 entity rows, 96 uint32/row
           const uint4* __restrict__ quat4,     // bf16 quat rows, 32 uint4/row
           const unsigned* __restrict__ hrp,
           const int* __restrict__ base,
           const int* __restrict__ partial, int nb,
           int n_ent, int E,
           float* __restrict__ out) {
    __shared__ int buf[256];
    {   // prologue: exclusive scan of chunk partials (redundant per block)
        const int tid = threadIdx.x;
        int v = (tid < nb) ? partial[tid] : 0;
        buf[tid] = v;
        __syncthreads();
        #pragma unroll
        for (int off = 1; off < 256; off <<= 1) {
            int x = (tid >= off) ? buf[tid - off] : 0;
            __syncthreads();
            buf[tid] += x;
            __syncthreads();
        }
        int ex = buf[tid] - v;
        __syncthreads();
        buf[tid] = ex;
        __syncthreads();
    }

    const int lane = threadIdx.x & 63;
    const int half = lane >> 5;           // edge slot 0..1
    const int j    = lane & 31;           // dim pair: dims 2j, 2j+1
    const int wid = (blockIdx.x * blockDim.x + threadIdx.x) >> 6;
    const int nw  = (gridDim.x * blockDim.x) >> 6;

    for (int t = wid; t < n_ent; t += nw) {
        int start = base[t] + buf[t >> 8];
        int end   = (t + 1 < n_ent) ? (base[t + 1] + buf[(t + 1) >> 8]) : E;
        v2f* o2 = (v2f*)(out + (size_t)t * (4 * HID));
        const int ob0 = half * 64 + j;     // v2f slots
        const int ob1 = ob0 + 32;
        if (start == end) {
            v2f z = {0.f, 0.f};
            o2[ob0] = z;
            o2[ob1] = z;
            continue;
        }
        int last = end - 1;

        const unsigned* kb = ent32 + (size_t)t * 96;
        unsigned ku0 = kb[j], ku1 = kb[32 + j], ku2 = kb[64 + j];
        v2f kx = {bflo(ku0), bfhi(ku0)};
        v2f ky = {bflo(ku1), bfhi(ku1)};
        v2f kz = {bflo(ku2), bfhi(ku2)};

        float dnm = 0.0f;
        v2f fx = {0.f, 0.f}, fy = fx, fz = fx, fw = fx;

        for (int kk = start; kk < end; kk += 2) {
            int e = kk + half;
            bool valid = (e < end);
            unsigned her = hrp[min(e, last)];
            unsigned hidx = her >> 9;
            unsigned ridx = her & 511u;

            const unsigned* hb = ent32 + (size_t)hidx * 96;
            unsigned u0 = hb[j], u1 = hb[32 + j], u2 = hb[64 + j];
            uint4 qa = quat4[ridx * 32 + j];

            v2f ex = {bflo(u0), bfhi(u0)};
            v2f ey = {bflo(u1), bfhi(u1)};
            v2f ez = {bflo(u2), bfhi(u2)};
            v2f w  = {bflo(qa.x), bflo(qa.z)};
            v2f ux = {bfhi(qa.x), bfhi(qa.z)};
            v2f uy = {bflo(qa.y), bflo(qa.w)};
            v2f uz = {bfhi(qa.y), bfhi(qa.w)};

            v2f rqx = w * ex + uy * ez - uz * ey;
            v2f rqy = w * ey + uz * ex - ux * ez;
            v2f rqz = w * ez + ux * ey - uy * ex;
            v2f rqw = -(ux * ex + uy * ey + uz * ez);

            v2f p2 = kx * rqx + ky * rqy + kz * rqz;
            float p = p2.x + p2.y;
            p += __shfl_xor(p, 1, 64);
            p += __shfl_xor(p, 2, 64);
            p += __shfl_xor(p, 4, 64);
            p += __shfl_xor(p, 8, 64);
            p += __shfl_xor(p, 16, 64);

            float pe = valid ? __expf(p * 0.0625f) : 0.0f;
            v2f pe2 = {pe, pe};
            dnm += pe;
            fx += pe2 * rqx;
            fy += pe2 * rqy;
            fz += pe2 * rqz;
            fw += pe2 * rqw;
        }

        // merge the two edge-slot halves (plain sums)
        dnm += __shfl_xor(dnm, 32, 64);
        fx.x += __shfl_xor(fx.x, 32, 64); fx.y += __shfl_xor(fx.y, 32, 64);
        fy.x += __shfl_xor(fy.x, 32, 64); fy.y += __shfl_xor(fy.y, 32, 64);
        fz.x += __shfl_xor(fz.x, 32, 64); fz.y += __shfl_xor(fz.y, 32, 64);
        fw.x += __shfl_xor(fw.x, 32, 64); fw.y += __shfl_xor(fw.y, 32, 64);

        float inv = (dnm > 0.0f) ? 1.0f / dnm : 0.0f;
        v2f s0 = half ? fz : fx;
        v2f s1 = half ? fw : fy;
        v2f r0 = {s0.x * inv, s0.y * inv};
        v2f r1 = {s1.x * inv, s1.y * inv};
        o2[ob0] = r0;
        o2[ob1] = r1;
    }
}

extern "C" void kernel_launch(void* const* d_in, const int* in_sizes, int n_in,
                              void* d_out, int out_size, void* d_ws, size_t ws_size,
                              hipStream_t stream) {
    const float* ent  = (const float*)d_in[0];
    const float* rel  = (const float*)d_in[1];
    const int*   eidx = (const int*)d_in[2];
    float* out = (float*)d_out;

    const int n_ent = in_sizes[0] / (3 * HID);
    const int n_rel = in_sizes[1] / (4 * HID);
    const int E     = in_sizes[2] / 3;

    // Workspace layout
    uint8_t* wp = (uint8_t*)d_ws;
    unsigned* hrp = (unsigned*)wp;                   wp += (size_t)E * 4;
    int*  hist    = (int*)wp;                        wp += (size_t)n_ent * 4;
    int*  base    = (int*)wp;                        wp += (size_t)n_ent * 4;
    int*  base2   = (int*)wp;                        wp += (size_t)n_ent * 4;
    int*  partial = (int*)wp;                        wp += 256 * 4;
    wp = (uint8_t*)(((uintptr_t)wp + 15) & ~(uintptr_t)15);
    uint2* quat16 = (uint2*)wp;                      wp += (size_t)n_rel * HID * sizeof(uint2);
    wp = (uint8_t*)(((uintptr_t)wp + 15) & ~(uintptr_t)15);
    uint4* ent16  = (uint4*)wp;                      wp += (size_t)n_ent * 3 * HID * 2;
    (void)ws_size;

    hipMemsetAsync(hist, 0, (size_t)n_ent * 4, stream);

    const int qblocks = (n_rel * HID + 255) / 256;
    const int eblocks = (E + 255) / 256;
    const int nconv   = n_ent * 3 * HID / 8;         // uint4 units
    const int cblocks = (nconv + 255) / 256;
    prep<<<qblocks + eblocks + cblocks, 256, 0, stream>>>(
        rel, quat16, n_rel, eidx, E, hist, ent, ent16, nconv, qblocks, eblocks);

    const int nb = (n_ent + 255) / 256;              // 196 (<=256)
    scan1<<<nb, 256, 0, stream>>>(hist, base, base2, partial, n_ent);

    scatter_hr<<<eblocks, 256, 0, stream>>>(eidx, E, partial, nb, base2, hrp);

    seg_reduce<<<2048, 256, 0, stream>>>((const unsigned*)ent16, (const uint4*)quat16,
                                         hrp, base, partial, nb, n_ent, E, out);
}